// Round 4
// baseline (1920.765 us; speedup 1.0000x reference)
//
#include <hip/hip_runtime.h>
#include <math.h>

// TransPhormer equivariant graph attention — round 3 (resubmit after infra timeout).
// N=10000, E=160000, MUL0=64, MUL1=32, M0=32, M1=16, H=8, NB=16, head dim 80
// cp layout (240): [0,48) = cp0 ; 48 + u*3 + c = cp1[u][c]
// qk layout per node: qkbuf[n*1920 + i*64 + lane], lane=(hh=lane&7, rr=lane>>3),
//   element = qk[hh][rr*30 + i]  (factored key: logit = <qk[src], cp> * SCALE)

constexpr float EPSV        = 1e-5f;
constexpr float INV_SQRT3   = 0.5773502691896258f;
constexpr float INV_SQRT2   = 0.7071067811865476f;
constexpr float INV_SQRT32  = 0.17677669529663687f;
constexpr float INV_SQRT48  = 0.14433756729740643f;
constexpr float INV_SQRT128 = 0.08838834764831845f;
constexpr float SCALE_ATT   = 0.14433756729740643f; // 1/sqrt(48)

#define LDS_FENCE() do { asm volatile("s_waitcnt lgkmcnt(0)" ::: "memory"); \
                         __builtin_amdgcn_sched_barrier(0); } while (0)

__device__ __forceinline__ float wsum64(float v) {
#pragma unroll
  for (int m = 1; m < 64; m <<= 1) v += __shfl_xor(v, m);
  return v;
}

// ---------------- sort-by-dst machinery ----------------
__global__ void init_count(unsigned* __restrict__ count, int N) {
  int i = blockIdx.x * blockDim.x + threadIdx.x;
  if (i < N) count[i] = 0u;
}

__global__ void k_hist(const int* __restrict__ edge_index, unsigned* __restrict__ count,
                       int E) {
  int e = blockIdx.x * blockDim.x + threadIdx.x;
  if (e < E) atomicAdd(&count[edge_index[(size_t)E + e]], 1u);
}

__global__ __launch_bounds__(1024) void k_scan(const unsigned* __restrict__ count,
                                               unsigned* __restrict__ offs,
                                               unsigned* __restrict__ cursor, int N) {
  __shared__ unsigned buf[1024];
  __shared__ unsigned carry;
  if (threadIdx.x == 0) carry = 0u;
  __syncthreads();
  for (int base = 0; base < N; base += 1024) {
    int i = base + threadIdx.x;
    unsigned v = (i < N) ? count[i] : 0u;
    buf[threadIdx.x] = v;
    __syncthreads();
    for (int off = 1; off < 1024; off <<= 1) {
      unsigned t = (threadIdx.x >= (unsigned)off) ? buf[threadIdx.x - off] : 0u;
      __syncthreads();
      buf[threadIdx.x] += t;
      __syncthreads();
    }
    unsigned excl = buf[threadIdx.x] - v + carry;
    if (i < N) { offs[i] = excl; cursor[i] = excl; }
    __syncthreads();
    if (threadIdx.x == 1023) carry += buf[1023];
    __syncthreads();
  }
  if (threadIdx.x == 0) offs[N] = carry;
}

__global__ void k_scatter(const int* __restrict__ edge_index, unsigned* __restrict__ cursor,
                          unsigned* __restrict__ sorted, int E) {
  int e = blockIdx.x * blockDim.x + threadIdx.x;
  if (e < E) {
    unsigned pos = atomicAdd(&cursor[edge_index[(size_t)E + e]], 1u);
    sorted[pos] = (unsigned)e;
  }
}

// ---------------- fused node-side: norm + q + s/d + factored qk ----------------
__global__ __launch_bounds__(512) void k_node(
    const float* __restrict__ node, const float* __restrict__ gamma0,
    const float* __restrict__ gamma1,
    const float* __restrict__ Wq0, const float* __restrict__ Wq1,
    const float* __restrict__ Wsrc0, const float* __restrict__ Wsrc1,
    const float* __restrict__ Wdst0, const float* __restrict__ Wdst1,
    const float* __restrict__ Wkv0, const float* __restrict__ Wkv1,
    float* __restrict__ qkbuf, float* __restrict__ sbuf, float* __restrict__ dbuf,
    int N) {
  // LDS: key-half weights staged (rotated to dodge bank conflicts) + per-wave h,q
  __shared__ float WL0[48 * 257];   // Wkv0 key half, rotated slots within h-block
  __shared__ float WL1[64 * 129];   // Wkv1 key half
  __shared__ float hW[8][160];
  __shared__ float qW[8][648];      // per head pitch 81

  int tid = threadIdx.x, wid = tid >> 6, lane = tid & 63;
  for (int idx = tid; idx < 48 * 256; idx += 512) {
    int j = idx >> 8, col = idx & 255, hb = col >> 5, m = col & 31;
    WL0[j * 257 + hb * 32 + ((m + 4 * hb) & 31)] = Wkv0[(size_t)j * 512 + col];
  }
  for (int idx = tid; idx < 64 * 128; idx += 512) {
    int u = idx >> 7, col = idx & 127;
    WL1[u * 129 + col] = Wkv1[(size_t)u * 256 + col];
  }
  __syncthreads();

  int hh = lane & 7, rr = lane >> 3;
  for (int n = blockIdx.x * 8 + wid; n < N; n += gridDim.x * 8) {
    const float* nrow = node + (size_t)n * 160;
    // ---- norms ----
    float v0 = nrow[lane];
    float mu = wsum64(v0) * (1.0f / 64.0f);
    float dv = v0 - mu;
    float var = wsum64(dv * dv) * (1.0f / 64.0f);
    float rs0 = rsqrtf(var + EPSV);
    float a = nrow[64 + lane];
    float b = (lane < 32) ? nrow[128 + lane] : 0.0f;
    float vn = wsum64(a * a + b * b) * (1.0f / 32.0f);
    float rs1 = rsqrtf(vn + EPSV);
    hW[wid][lane] = dv * rs0 * gamma0[lane];
    hW[wid][64 + lane] = a * rs1 * gamma1[lane / 3];
    if (lane < 32) hW[wid][128 + lane] = b * rs1 * gamma1[(64 + lane) / 3];
    LDS_FENCE();

    // ---- q0: col = h*32+m, coalesced weight reads ----
#pragma unroll
    for (int g = 0; g < 4; g++) {
      int col = g * 64 + lane;
      float acc = 0.f;
#pragma unroll
      for (int k = 0; k < 64; k++) acc += hW[wid][k] * Wq0[k * 256 + col];
      qW[wid][(col >> 5) * 81 + (col & 31)] = acc * 0.125f;
    }
    // ---- q1: col2 = h*16+t ----
#pragma unroll
    for (int g = 0; g < 2; g++) {
      int col2 = g * 64 + lane;
      int h2 = col2 >> 4, t = col2 & 15;
#pragma unroll
      for (int c = 0; c < 3; c++) {
        float acc = 0.f;
#pragma unroll
        for (int u = 0; u < 32; u++) acc += hW[wid][64 + u * 3 + c] * Wq1[u * 128 + col2];
        qW[wid][h2 * 81 + 32 + t * 3 + c] = acc * INV_SQRT32;
      }
    }
    LDS_FENCE();

    // ---- s/d scalar ----
    {
      int which = lane >> 5, j = lane & 31;
      const float* W0 = which ? Wdst0 : Wsrc0;
      float acc = 0.f;
#pragma unroll
      for (int k = 0; k < 64; k++) acc += hW[wid][k] * W0[k * 32 + j];
      (which ? dbuf : sbuf)[(size_t)n * 80 + j] = acc * 0.125f;
    }
    // ---- s/d vector ----
#pragma unroll
    for (int i0 = 0; i0 < 96; i0 += 64) {
      int i = i0 + lane;
      if (i < 96) {
        int which = (i >= 48);
        int vc = which ? i - 48 : i;
        int v = vc / 3, c = vc - v * 3;
        const float* W1 = which ? Wdst1 : Wsrc1;
        float acc = 0.f;
#pragma unroll
        for (int u = 0; u < 32; u++) acc += hW[wid][64 + u * 3 + c] * W1[u * 16 + v];
        (which ? dbuf : sbuf)[(size_t)n * 80 + 32 + vc] = acc * INV_SQRT32;
      }
    }

    // ---- factored qk: lane (hh, rr), elems j = rr*30 + i ----
    float* qkrow = qkbuf + (size_t)n * 1920;
#pragma unroll
    for (int i = 0; i < 30; i++) {
      int j = rr * 30 + i;
      float acc = 0.f, val;
      if (j < 48) {
#pragma unroll
        for (int k = 0; k < 32; k++)
          acc += qW[wid][hh * 81 + k] * WL0[j * 257 + hh * 32 + ((k + 4 * hh) & 31)];
        val = acc * INV_SQRT48;
      } else {
        int u = (j - 48) / 3, c = (j - 48) - u * 3;
#pragma unroll
        for (int t = 0; t < 16; t++)
          acc += qW[wid][hh * 81 + 32 + t * 3 + c] * WL1[u * 129 + hh * 16 + t];
        val = acc * 0.125f;
      }
      qkrow[i * 64 + lane] = val;
    }
  }
}

// ---------------- fused per-node: online-softmax aggregation + value GEMM ----------------
__global__ __launch_bounds__(256, 3) void k_agg(
    const float* __restrict__ rbf, const float* __restrict__ rsh,
    const int* __restrict__ edge_index,
    const float* __restrict__ W_rbf, const float* __restrict__ Wkv0,
    const float* __restrict__ Wkv1,
    const float* __restrict__ qkbuf, const float* __restrict__ sbuf,
    const float* __restrict__ dbuf,
    const unsigned* __restrict__ offs, const unsigned* __restrict__ sorted,
    float* __restrict__ mlbuf, int N, int E) {
  __shared__ float S[4 * 2360];   // per wave: x 80 | w 112 | cp 240 | acp 8*241
  int tid = threadIdx.x, wid = tid >> 6, lane = tid & 63;
  int hh = lane & 7, rr = lane >> 3;
  float* xw = S + wid * 2360;
  float* ww = xw + 80;
  float* cpL = xw + 192;
  float* acpL = xw + 432;

  int n = blockIdx.x * 4 + wid;
  if (n >= N) return;
  unsigned off = offs[n];
  int deg = (int)(offs[n + 1] - off);
  float* mlrow = mlbuf + (size_t)n * 640;
  if (deg == 0) {
#pragma unroll
    for (int g = 0; g < 10; g++) mlrow[g * 64 + lane] = 0.f;
    return;
  }

  float xd0 = dbuf[(size_t)n * 80 + lane];
  float xd1 = (lane < 16) ? dbuf[(size_t)n * 80 + 64 + lane] : 0.f;

  float m = -3.4e38f, z = 0.f;
  float acc[30];
#pragma unroll
  for (int i = 0; i < 30; i++) acc[i] = 0.f;

  unsigned e = sorted[off];
  int src = edge_index[e];
  for (int t = 0; t < deg; t++) {
    unsigned e_next = 0; int src_next = 0;
    if (t + 1 < deg) { e_next = sorted[off + t + 1]; src_next = edge_index[e_next]; }

    // early global loads (overlap with cp build)
    float qkv[30];
    const float* qkr = qkbuf + (size_t)src * 1920;
#pragma unroll
    for (int i = 0; i < 30; i++) qkv[i] = qkr[i * 64 + lane];
    const float* srow = sbuf + (size_t)src * 80;
    float sx0 = srow[lane];
    float sx1 = (lane < 16) ? srow[64 + lane] : 0.f;

    // x = s[src] + d[n]
    xw[lane] = sx0 + xd0;
    if (lane < 16) xw[64 + lane] = sx1 + xd1;
    // w = rbf[e] @ W_rbf
    const float* rrow = rbf + (size_t)e * 16;
    for (int j = lane; j < 112; j += 64) {
      float acw = 0.f;
#pragma unroll
      for (int k = 0; k < 16; k++) acw += rrow[k] * W_rbf[k * 112 + j];
      ww[j] = acw;
    }
    LDS_FENCE();

    float y0 = rsh[(size_t)e * 4], ya = rsh[(size_t)e * 4 + 1];
    float yb = rsh[(size_t)e * 4 + 2], yc = rsh[(size_t)e * 4 + 3];
    if (lane < 48) {
      float v;
      if (lane < 32) v = ww[lane] * xw[lane] * y0;
      else {
        int u = lane - 32;
        float dp = xw[32 + u * 3] * ya + xw[32 + u * 3 + 1] * yb + xw[32 + u * 3 + 2] * yc;
        v = ww[32 + u] * dp * INV_SQRT3;
      }
      cpL[lane] = v;
    }
    {
      int u = lane; float c0, c1, c2;
      if (u < 32) {
        float aw = ww[48 + u] * xw[u];
        c0 = aw * ya; c1 = aw * yb; c2 = aw * yc;
      } else if (u < 48) {
        int t2 = u - 32; float wv = ww[80 + t2] * y0;
        c0 = wv * xw[32 + t2 * 3]; c1 = wv * xw[32 + t2 * 3 + 1]; c2 = wv * xw[32 + t2 * 3 + 2];
      } else {
        int t2 = u - 48;
        float x0 = xw[32 + t2 * 3], x1 = xw[32 + t2 * 3 + 1], x2 = xw[32 + t2 * 3 + 2];
        float wv = ww[96 + t2] * INV_SQRT2;
        c0 = wv * (x1 * yc - x2 * yb);
        c1 = wv * (x2 * ya - x0 * yc);
        c2 = wv * (x0 * yb - x1 * ya);
      }
      cpL[48 + u * 3] = c0; cpL[48 + u * 3 + 1] = c1; cpL[48 + u * 3 + 2] = c2;
    }
    LDS_FENCE();

    // logit via factored qk dot
    float part = 0.f;
#pragma unroll
    for (int i = 0; i < 30; i++) part += qkv[i] * cpL[rr * 30 + i];
    part += __shfl_xor(part, 8);
    part += __shfl_xor(part, 16);
    part += __shfl_xor(part, 32);
    float lg = part * SCALE_ATT;

    // online softmax update (branchless)
    float mn = fmaxf(m, lg);
    float sc = expf(m - mn);
    float aa = expf(lg - mn);
    z = z * sc + aa;
#pragma unroll
    for (int i = 0; i < 30; i++) acc[i] = acc[i] * sc + aa * cpL[rr * 30 + i];
    m = mn;
    LDS_FENCE();
    e = e_next; src = src_next;
  }

  // stage acp = sum a*cp to LDS for arbitrary-index value GEMM
#pragma unroll
  for (int i = 0; i < 30; i++) acpL[hh * 241 + rr * 30 + i] = acc[i];
  LDS_FENCE();

  // value GEMM (coalesced global weight reads) + normalize
#pragma unroll
  for (int g = 0; g < 4; g++) {
    int col = g * 64 + lane;       // h*32+m
    int h2 = col >> 5;
    float a2 = 0.f;
#pragma unroll
    for (int k = 0; k < 48; k++) a2 += acpL[h2 * 241 + k] * Wkv0[k * 512 + 256 + col];
    float zz = __shfl(z, h2);
    mlrow[col] = a2 * INV_SQRT48 / (zz + 1e-16f);
  }
#pragma unroll
  for (int g = 0; g < 6; g++) {
    int pc = g * 64 + lane;        // p*3+c, p = h*16+u
    int p = pc / 3, c = pc - p * 3;
    int h2 = p >> 4;
    float a2 = 0.f;
#pragma unroll
    for (int w = 0; w < 64; w++)
      a2 += acpL[h2 * 241 + 48 + w * 3 + c] * Wkv1[w * 256 + 128 + p];
    float zz = __shfl(z, h2);
    mlrow[256 + pc] = a2 * 0.125f / (zz + 1e-16f);
  }
}

// ---------------- output projection + residual ----------------
__global__ __launch_bounds__(256) void k_out(
    const float* __restrict__ node, const float* __restrict__ mlbuf,
    const float* __restrict__ Wmsg0, const float* __restrict__ Wmsg1,
    float* __restrict__ out, int N) {
  __shared__ float mlw[4][640];
  int tid = threadIdx.x, wid = tid >> 6, lane = tid & 63;
  int n = blockIdx.x * 4 + wid;
  if (n >= N) return;
  const float* mlrow = mlbuf + (size_t)n * 640;
#pragma unroll
  for (int g = 0; g < 10; g++) mlw[wid][g * 64 + lane] = mlrow[g * 64 + lane];
  LDS_FENCE();
  const float* nrow = node + (size_t)n * 160;
  float* orow = out + (size_t)n * 160;
  {
    float a2 = 0.f;
#pragma unroll 8
    for (int j = 0; j < 256; j++) a2 += mlw[wid][j] * Wmsg0[j * 64 + lane];
    orow[lane] = nrow[lane] + a2 * 0.0625f;
  }
#pragma unroll
  for (int i0 = 0; i0 < 96; i0 += 64) {
    int i = i0 + lane;
    if (i < 96) {
      int v = i / 3, c = i - v * 3;
      float a2 = 0.f;
#pragma unroll 8
      for (int p = 0; p < 128; p++) a2 += mlw[wid][256 + p * 3 + c] * Wmsg1[p * 32 + v];
      orow[64 + i] = nrow[64 + i] + a2 * INV_SQRT128;
    }
  }
}

extern "C" void kernel_launch(void* const* d_in, const int* in_sizes, int n_in,
                              void* d_out, int out_size, void* d_ws, size_t ws_size,
                              hipStream_t stream) {
  (void)n_in; (void)out_size; (void)ws_size;
  const float* node   = (const float*)d_in[0];
  const float* rbf    = (const float*)d_in[1];
  const float* rsh    = (const float*)d_in[2];
  const int*   eidx   = (const int*)d_in[3];
  const float* gamma0 = (const float*)d_in[4];
  const float* gamma1 = (const float*)d_in[5];
  const float* Wq0    = (const float*)d_in[6];
  const float* Wq1    = (const float*)d_in[7];
  const float* Wsrc0  = (const float*)d_in[8];
  const float* Wsrc1  = (const float*)d_in[9];
  const float* Wdst0  = (const float*)d_in[10];
  const float* Wdst1  = (const float*)d_in[11];
  const float* W_rbf  = (const float*)d_in[12];
  const float* Wkv0   = (const float*)d_in[13];
  const float* Wkv1   = (const float*)d_in[14];
  const float* Wmsg0  = (const float*)d_in[15];
  const float* Wmsg1  = (const float*)d_in[16];
  float* out = (float*)d_out;

  int N = in_sizes[0] / 160;
  int E = in_sizes[3] / 2;

  float* sbuf   = (float*)d_ws;                    // N*80
  float* dbuf   = sbuf + (size_t)N * 80;           // N*80
  float* qkbuf  = dbuf + (size_t)N * 80;           // N*1920
  float* mlbuf  = qkbuf + (size_t)N * 1920;        // N*640
  unsigned* count  = (unsigned*)(mlbuf + (size_t)N * 640);  // N
  unsigned* offs   = count + N;                             // N+1
  unsigned* cursor = offs + N + 1;                          // N
  unsigned* sorted = cursor + N;                            // E

  hipLaunchKernelGGL(init_count, dim3((N + 255) / 256), dim3(256), 0, stream, count, N);
  hipLaunchKernelGGL(k_hist, dim3((E + 255) / 256), dim3(256), 0, stream, eidx, count, E);
  hipLaunchKernelGGL(k_scan, dim3(1), dim3(1024), 0, stream, count, offs, cursor, N);
  hipLaunchKernelGGL(k_scatter, dim3((E + 255) / 256), dim3(256), 0, stream,
                     eidx, cursor, sorted, E);
  hipLaunchKernelGGL(k_node, dim3(256), dim3(512), 0, stream,
                     node, gamma0, gamma1, Wq0, Wq1, Wsrc0, Wsrc1, Wdst0, Wdst1,
                     Wkv0, Wkv1, qkbuf, sbuf, dbuf, N);
  hipLaunchKernelGGL(k_agg, dim3((N + 3) / 4), dim3(256), 0, stream,
                     rbf, rsh, eidx, W_rbf, Wkv0, Wkv1, qkbuf, sbuf, dbuf,
                     offs, sorted, mlbuf, N, E);
  hipLaunchKernelGGL(k_out, dim3((N + 3) / 4), dim3(256), 0, stream,
                     node, mlbuf, Wmsg0, Wmsg1, out, N);
}

// Round 5
// 831.618 us; speedup vs baseline: 2.3097x; 2.3097x over previous
//
#include <hip/hip_runtime.h>
#include <math.h>

// TransPhormer equivariant graph attention — round 5.
// Key change vs r3: node-side q is algebraically folded into the key weights:
//   qk_scalar[h][j]   = sum_k  h0[k]    * WAT[k][h*48+j]
//   qk_vec[h][u][c]   = sum_u' h1[u'][c]* WBT[u'][h*64+u]
// WAT/WBT precomputed on-device each launch (k_wfold), stored bf16-packed,
// staged in LDS once per block; 16 nodes batched per block -> no per-node
// global weight re-reads (r3's 721 MB HBM fetch pathology).
// qk layout per node: qkbuf[n*1920 + i*64 + lane], lane=(hh=lane&7, rr=lane>>3),
//   element = qk[hh][J=rr*30+i]; J<48 scalar, else u=(J-48)/3, c=(J-48)%3.

constexpr float EPSV        = 1e-5f;
constexpr float INV_SQRT3   = 0.5773502691896258f;
constexpr float INV_SQRT2   = 0.7071067811865476f;
constexpr float INV_SQRT32  = 0.17677669529663687f;
constexpr float INV_SQRT48  = 0.14433756729740643f;
constexpr float INV_SQRT128 = 0.08838834764831845f;
constexpr float SCALE_ATT   = 0.14433756729740643f; // 1/sqrt(48)

#define LDS_FENCE() do { asm volatile("s_waitcnt lgkmcnt(0)" ::: "memory"); \
                         __builtin_amdgcn_sched_barrier(0); } while (0)

__device__ __forceinline__ float wsum64(float v) {
#pragma unroll
  for (int m = 1; m < 64; m <<= 1) v += __shfl_xor(v, m);
  return v;
}

__device__ __forceinline__ unsigned bf16r(float f) {
  unsigned b = __float_as_uint(f);
  return (b + 0x7FFFu + ((b >> 16) & 1u)) >> 16;
}

// ---------------- sort-by-dst machinery ----------------
__global__ void init_count(unsigned* __restrict__ count, int N) {
  int i = blockIdx.x * blockDim.x + threadIdx.x;
  if (i < N) count[i] = 0u;
}

__global__ void k_hist(const int* __restrict__ edge_index, unsigned* __restrict__ count,
                       int E) {
  int e = blockIdx.x * blockDim.x + threadIdx.x;
  if (e < E) atomicAdd(&count[edge_index[(size_t)E + e]], 1u);
}

__global__ __launch_bounds__(1024) void k_scan(const unsigned* __restrict__ count,
                                               unsigned* __restrict__ offs,
                                               unsigned* __restrict__ cursor, int N) {
  __shared__ unsigned buf[1024];
  __shared__ unsigned carry;
  if (threadIdx.x == 0) carry = 0u;
  __syncthreads();
  for (int base = 0; base < N; base += 1024) {
    int i = base + threadIdx.x;
    unsigned v = (i < N) ? count[i] : 0u;
    buf[threadIdx.x] = v;
    __syncthreads();
    for (int off = 1; off < 1024; off <<= 1) {
      unsigned t = (threadIdx.x >= (unsigned)off) ? buf[threadIdx.x - off] : 0u;
      __syncthreads();
      buf[threadIdx.x] += t;
      __syncthreads();
    }
    unsigned excl = buf[threadIdx.x] - v + carry;
    if (i < N) { offs[i] = excl; cursor[i] = excl; }
    __syncthreads();
    if (threadIdx.x == 1023) carry += buf[1023];
    __syncthreads();
  }
  if (threadIdx.x == 0) offs[N] = carry;
}

__global__ void k_scatter(const int* __restrict__ edge_index, unsigned* __restrict__ cursor,
                          unsigned* __restrict__ sorted, int E) {
  int e = blockIdx.x * blockDim.x + threadIdx.x;
  if (e < E) {
    unsigned pos = atomicAdd(&cursor[edge_index[(size_t)E + e]], 1u);
    sorted[pos] = (unsigned)e;
  }
}

// ---------------- fold q-projection into key weights ----------------
// WATp: [k2<32][o<384] packed bf16x2 over k={2k2,2k2+1}; o = h*48+j
// WBTp: [u2<16][o2<512] packed bf16x2 over u'={2u2,2u2+1}; o2 = h*64+u
__global__ __launch_bounds__(256) void k_wfold(
    const float* __restrict__ Wq0, const float* __restrict__ Wq1,
    const float* __restrict__ Wkv0, const float* __restrict__ Wkv1,
    unsigned* __restrict__ WATp, unsigned* __restrict__ WBTp) {
  int idx = blockIdx.x * 256 + threadIdx.x;
  if (idx < 32 * 384) {
    int k2 = idx / 384, o = idx % 384;
    int h = o / 48, j = o % 48;
    const float* wq0 = Wq0 + (size_t)(2 * k2) * 256 + h * 32;
    const float* wq1 = Wq0 + (size_t)(2 * k2 + 1) * 256 + h * 32;
    const float* wk  = Wkv0 + (size_t)j * 512 + h * 32;
    float s0 = 0.f, s1 = 0.f;
#pragma unroll
    for (int m = 0; m < 32; m++) { s0 += wq0[m] * wk[m]; s1 += wq1[m] * wk[m]; }
    s0 *= 0.125f * INV_SQRT48; s1 *= 0.125f * INV_SQRT48;
    WATp[idx] = bf16r(s0) | (bf16r(s1) << 16);
  }
  idx -= 32 * 384;
  if (idx >= 0 && idx < 16 * 512) {
    int u2 = idx / 512, o2 = idx % 512;
    int h = o2 / 64, u = o2 % 64;
    const float* wa = Wq1 + (size_t)(2 * u2) * 128 + h * 16;
    const float* wb = Wq1 + (size_t)(2 * u2 + 1) * 128 + h * 16;
    const float* wk = Wkv1 + (size_t)u * 256 + h * 16;
    float s0 = 0.f, s1 = 0.f;
#pragma unroll
    for (int t = 0; t < 16; t++) { s0 += wa[t] * wk[t]; s1 += wb[t] * wk[t]; }
    s0 *= 0.125f * INV_SQRT32; s1 *= 0.125f * INV_SQRT32;
    WBTp[idx] = bf16r(s0) | (bf16r(s1) << 16);
  }
}

// ---------------- node-side: norms + qk (folded) + s/d, 16 nodes/block --------
__global__ __launch_bounds__(256) void k_node(
    const float* __restrict__ node, const float* __restrict__ gamma0,
    const float* __restrict__ gamma1,
    const unsigned* __restrict__ WATp, const unsigned* __restrict__ WBTp,
    const float* __restrict__ Wsrc0, const float* __restrict__ Wsrc1,
    const float* __restrict__ Wdst0, const float* __restrict__ Wdst1,
    float* __restrict__ qkbuf, float* __restrict__ sbuf, float* __restrict__ dbuf,
    int N) {
  __shared__ unsigned WATL[32 * 384];   // 49152 B
  __shared__ unsigned WBTL[16 * 512];   // 32768 B
  __shared__ float    hL[16][160];      // 10240 B
  __shared__ float    Wsd0L[64 * 64];   // [k][which*32+j] 16384 B
  __shared__ float    Wsd1L[32 * 32];   // [u'][which*16+v] 4096 B

  int t = threadIdx.x;
  for (int i = t; i < 32 * 384; i += 256) WATL[i] = WATp[i];
  for (int i = t; i < 16 * 512; i += 256) WBTL[i] = WBTp[i];
  for (int i = t; i < 64 * 64; i += 256) {
    int k = i >> 6, o3 = i & 63, wh = o3 >> 5, j = o3 & 31;
    Wsd0L[i] = (wh ? Wdst0 : Wsrc0)[k * 32 + j];
  }
  for (int i = t; i < 32 * 32; i += 256) {
    int u = i >> 5, o4 = i & 31, wh = o4 >> 4, v = o4 & 15;
    Wsd1L[i] = (wh ? Wdst1 : Wsrc1)[u * 16 + v];
  }

  int wid = t >> 6, lane = t & 63;
  int n0 = blockIdx.x * 16;
  int nmax = min(16, N - n0);
  if (nmax <= 0) return;

  // norms: wave wid handles local nodes wid*4 .. wid*4+3
  for (int nl = wid * 4; nl < min(wid * 4 + 4, nmax); nl++) {
    const float* nrow = node + (size_t)(n0 + nl) * 160;
    float v0 = nrow[lane];
    float mu = wsum64(v0) * (1.0f / 64.0f);
    float dv = v0 - mu;
    float var = wsum64(dv * dv) * (1.0f / 64.0f);
    float rs0 = rsqrtf(var + EPSV);
    float a = nrow[64 + lane];
    float b = (lane < 32) ? nrow[128 + lane] : 0.0f;
    float vn = wsum64(a * a + b * b) * (1.0f / 32.0f);
    float rs1 = rsqrtf(vn + EPSV);
    hL[nl][lane] = dv * rs0 * gamma0[lane];
    hL[nl][64 + lane] = a * rs1 * gamma1[lane / 3];
    if (lane < 32) hL[nl][128 + lane] = b * rs1 * gamma1[(64 + lane) / 3];
  }
  __syncthreads();

  // ---- qk GEMM: thread owns storage positions p = t + 256*s ----
  int hh = lane & 7, rr = lane >> 3;
  int i0 = t >> 6;
  for (int s = 0; s < 8; s++) {
    int i = i0 + 4 * s;
    if (i >= 30) break;
    int J = rr * 30 + i;
    float acc[16];
#pragma unroll
    for (int n = 0; n < 16; n++) acc[n] = 0.f;
    if (J < 48) {
      int o = hh * 48 + J;
#pragma unroll 2
      for (int k2 = 0; k2 < 32; k2++) {
        unsigned pr = WATL[k2 * 384 + o];
        float w0 = __uint_as_float(pr << 16);
        float w1 = __uint_as_float(pr & 0xFFFF0000u);
#pragma unroll
        for (int n = 0; n < 16; n++) {
          float2 hp = *reinterpret_cast<const float2*>(&hL[n][2 * k2]);
          acc[n] += hp.x * w0 + hp.y * w1;
        }
      }
    } else {
      int u = (J - 48) / 3, c = (J - 48) - 3 * u;
      int o2 = hh * 64 + u;
#pragma unroll 2
      for (int u2 = 0; u2 < 16; u2++) {
        unsigned pr = WBTL[u2 * 512 + o2];
        float w0 = __uint_as_float(pr << 16);
        float w1 = __uint_as_float(pr & 0xFFFF0000u);
#pragma unroll
        for (int n = 0; n < 16; n++)
          acc[n] += hL[n][64 + (2 * u2) * 3 + c] * w0 +
                    hL[n][64 + (2 * u2 + 1) * 3 + c] * w1;
      }
    }
    for (int n = 0; n < nmax; n++)
      qkbuf[(size_t)(n0 + n) * 1920 + i * 64 + lane] = acc[n];
  }

  // ---- s/d projections ----
  if (t < 64) {
    int wh = t >> 5, j = t & 31;
    float acc[16];
#pragma unroll
    for (int n = 0; n < 16; n++) acc[n] = 0.f;
    for (int k = 0; k < 64; k++) {
      float w = Wsd0L[k * 64 + t];
#pragma unroll
      for (int n = 0; n < 16; n++) acc[n] += hL[n][k] * w;
    }
    float* obuf = wh ? dbuf : sbuf;
    for (int n = 0; n < nmax; n++) obuf[(size_t)(n0 + n) * 80 + j] = acc[n] * 0.125f;
  } else if (t < 160) {
    int idx = t - 64;                 // 0..95
    int wh = idx / 48, vc = idx % 48, v = vc / 3, c = vc - 3 * v;
    float acc[16];
#pragma unroll
    for (int n = 0; n < 16; n++) acc[n] = 0.f;
    for (int u = 0; u < 32; u++) {
      float w = Wsd1L[u * 32 + wh * 16 + v];
#pragma unroll
      for (int n = 0; n < 16; n++) acc[n] += hL[n][64 + u * 3 + c] * w;
    }
    float* obuf = wh ? dbuf : sbuf;
    for (int n = 0; n < nmax; n++)
      obuf[(size_t)(n0 + n) * 80 + 32 + vc] = acc[n] * INV_SQRT32;
  }
}

// ---------------- fused per-node: online-softmax aggregation + value GEMM ------
__global__ __launch_bounds__(256, 4) void k_agg(
    const float* __restrict__ rbf, const float* __restrict__ rsh,
    const int* __restrict__ edge_index,
    const float* __restrict__ W_rbf, const float* __restrict__ Wkv0,
    const float* __restrict__ Wkv1,
    const float* __restrict__ qkbuf, const float* __restrict__ sbuf,
    const float* __restrict__ dbuf,
    const unsigned* __restrict__ offs, const unsigned* __restrict__ sorted,
    float* __restrict__ mlbuf, int N, int E) {
  // per-wave 1952 floats; acp (1928) overlaps the per-edge scratch (dead by then)
  __shared__ float S[4 * 1952];
  int tid = threadIdx.x, wid = tid >> 6, lane = tid & 63;
  int hh = lane & 7, rr = lane >> 3;
  float* acpL = S + wid * 1952;
  float* xw   = acpL;          // 80
  float* ww   = acpL + 80;     // 112
  float* cpL  = acpL + 192;    // 240

  int n = blockIdx.x * 4 + wid;
  if (n >= N) return;
  unsigned off = offs[n];
  int deg = (int)(offs[n + 1] - off);
  float* mlrow = mlbuf + (size_t)n * 640;
  if (deg == 0) {
#pragma unroll
    for (int g = 0; g < 10; g++) mlrow[g * 64 + lane] = 0.f;
    return;
  }

  float xd0 = dbuf[(size_t)n * 80 + lane];
  float xd1 = (lane < 16) ? dbuf[(size_t)n * 80 + 64 + lane] : 0.f;

  float m = -3.4e38f, z = 0.f;
  float acc[30];
#pragma unroll
  for (int i = 0; i < 30; i++) acc[i] = 0.f;

  unsigned e = sorted[off];
  int src = edge_index[e];
  for (int t = 0; t < deg; t++) {
    unsigned e_next = 0; int src_next = 0;
    if (t + 1 < deg) { e_next = sorted[off + t + 1]; src_next = edge_index[e_next]; }

    // early global loads (overlap with cp build)
    float qkv[30];
    const float* qkr = qkbuf + (size_t)src * 1920;
#pragma unroll
    for (int i = 0; i < 30; i++) qkv[i] = qkr[i * 64 + lane];
    const float* srow = sbuf + (size_t)src * 80;
    float sx0 = srow[lane];
    float sx1 = (lane < 16) ? srow[64 + lane] : 0.f;

    xw[lane] = sx0 + xd0;
    if (lane < 16) xw[64 + lane] = sx1 + xd1;
    const float* rrow = rbf + (size_t)e * 16;
    for (int j = lane; j < 112; j += 64) {
      float acw = 0.f;
#pragma unroll
      for (int k = 0; k < 16; k++) acw += rrow[k] * W_rbf[k * 112 + j];
      ww[j] = acw;
    }
    LDS_FENCE();

    float y0 = rsh[(size_t)e * 4], ya = rsh[(size_t)e * 4 + 1];
    float yb = rsh[(size_t)e * 4 + 2], yc = rsh[(size_t)e * 4 + 3];
    if (lane < 48) {
      float v;
      if (lane < 32) v = ww[lane] * xw[lane] * y0;
      else {
        int u = lane - 32;
        float dp = xw[32 + u * 3] * ya + xw[32 + u * 3 + 1] * yb + xw[32 + u * 3 + 2] * yc;
        v = ww[32 + u] * dp * INV_SQRT3;
      }
      cpL[lane] = v;
    }
    {
      int u = lane; float c0, c1, c2;
      if (u < 32) {
        float aw = ww[48 + u] * xw[u];
        c0 = aw * ya; c1 = aw * yb; c2 = aw * yc;
      } else if (u < 48) {
        int t2 = u - 32; float wv = ww[80 + t2] * y0;
        c0 = wv * xw[32 + t2 * 3]; c1 = wv * xw[32 + t2 * 3 + 1]; c2 = wv * xw[32 + t2 * 3 + 2];
      } else {
        int t2 = u - 48;
        float x0 = xw[32 + t2 * 3], x1 = xw[32 + t2 * 3 + 1], x2 = xw[32 + t2 * 3 + 2];
        float wv = ww[96 + t2] * INV_SQRT2;
        c0 = wv * (x1 * yc - x2 * yb);
        c1 = wv * (x2 * ya - x0 * yc);
        c2 = wv * (x0 * yb - x1 * ya);
      }
      cpL[48 + u * 3] = c0; cpL[48 + u * 3 + 1] = c1; cpL[48 + u * 3 + 2] = c2;
    }
    LDS_FENCE();

    float part = 0.f;
#pragma unroll
    for (int i = 0; i < 30; i++) part += qkv[i] * cpL[rr * 30 + i];
    part += __shfl_xor(part, 8);
    part += __shfl_xor(part, 16);
    part += __shfl_xor(part, 32);
    float lg = part * SCALE_ATT;

    float mn = fmaxf(m, lg);
    float sc = expf(m - mn);
    float aa = expf(lg - mn);
    z = z * sc + aa;
#pragma unroll
    for (int i = 0; i < 30; i++) acc[i] = acc[i] * sc + aa * cpL[rr * 30 + i];
    m = mn;
    LDS_FENCE();
    e = e_next; src = src_next;
  }

  // stage acp (overlaps dead scratch)
#pragma unroll
  for (int i = 0; i < 30; i++) acpL[hh * 241 + rr * 30 + i] = acc[i];
  LDS_FENCE();

  // value GEMM + normalize
#pragma unroll
  for (int g = 0; g < 4; g++) {
    int col = g * 64 + lane;       // h*32+m
    int h2 = col >> 5;
    float a2 = 0.f;
#pragma unroll
    for (int k = 0; k < 48; k++) a2 += acpL[h2 * 241 + k] * Wkv0[k * 512 + 256 + col];
    float zz = __shfl(z, h2);
    mlrow[col] = a2 * INV_SQRT48 / (zz + 1e-16f);
  }
#pragma unroll
  for (int g = 0; g < 6; g++) {
    int pc = g * 64 + lane;        // p*3+c, p = h*16+u
    int p = pc / 3, c = pc - p * 3;
    int h2 = p >> 4;
    float a2 = 0.f;
#pragma unroll
    for (int w = 0; w < 64; w++)
      a2 += acpL[h2 * 241 + 48 + w * 3 + c] * Wkv1[w * 256 + 128 + p];
    float zz = __shfl(z, h2);
    mlrow[256 + pc] = a2 * 0.125f / (zz + 1e-16f);
  }
}

// ---------------- output projection + residual ----------------
__global__ __launch_bounds__(256) void k_out(
    const float* __restrict__ node, const float* __restrict__ mlbuf,
    const float* __restrict__ Wmsg0, const float* __restrict__ Wmsg1,
    float* __restrict__ out, int N) {
  __shared__ float mlw[4][640];
  int tid = threadIdx.x, wid = tid >> 6, lane = tid & 63;
  int n = blockIdx.x * 4 + wid;
  if (n >= N) return;
  const float* mlrow = mlbuf + (size_t)n * 640;
#pragma unroll
  for (int g = 0; g < 10; g++) mlw[wid][g * 64 + lane] = mlrow[g * 64 + lane];
  LDS_FENCE();
  const float* nrow = node + (size_t)n * 160;
  float* orow = out + (size_t)n * 160;
  {
    float a2 = 0.f;
#pragma unroll 8
    for (int j = 0; j < 256; j++) a2 += mlw[wid][j] * Wmsg0[j * 64 + lane];
    orow[lane] = nrow[lane] + a2 * 0.0625f;
  }
#pragma unroll
  for (int i0 = 0; i0 < 96; i0 += 64) {
    int i = i0 + lane;
    if (i < 96) {
      int v = i / 3, c = i - v * 3;
      float a2 = 0.f;
#pragma unroll 8
      for (int p = 0; p < 128; p++) a2 += mlw[wid][256 + p * 3 + c] * Wmsg1[p * 32 + v];
      orow[64 + i] = nrow[64 + i] + a2 * INV_SQRT128;
    }
  }
}

extern "C" void kernel_launch(void* const* d_in, const int* in_sizes, int n_in,
                              void* d_out, int out_size, void* d_ws, size_t ws_size,
                              hipStream_t stream) {
  (void)n_in; (void)out_size; (void)ws_size;
  const float* node   = (const float*)d_in[0];
  const float* rbf    = (const float*)d_in[1];
  const float* rsh    = (const float*)d_in[2];
  const int*   eidx   = (const int*)d_in[3];
  const float* gamma0 = (const float*)d_in[4];
  const float* gamma1 = (const float*)d_in[5];
  const float* Wq0    = (const float*)d_in[6];
  const float* Wq1    = (const float*)d_in[7];
  const float* Wsrc0  = (const float*)d_in[8];
  const float* Wsrc1  = (const float*)d_in[9];
  const float* Wdst0  = (const float*)d_in[10];
  const float* Wdst1  = (const float*)d_in[11];
  const float* W_rbf  = (const float*)d_in[12];
  const float* Wkv0   = (const float*)d_in[13];
  const float* Wkv1   = (const float*)d_in[14];
  const float* Wmsg0  = (const float*)d_in[15];
  const float* Wmsg1  = (const float*)d_in[16];
  float* out = (float*)d_out;

  int N = in_sizes[0] / 160;
  int E = in_sizes[3] / 2;

  unsigned* WATp = (unsigned*)d_ws;                       // 32*384
  unsigned* WBTp = WATp + 32 * 384;                       // 16*512
  float* sbuf   = (float*)(WBTp + 16 * 512);              // N*80
  float* dbuf   = sbuf + (size_t)N * 80;                  // N*80
  float* qkbuf  = dbuf + (size_t)N * 80;                  // N*1920
  float* mlbuf  = qkbuf + (size_t)N * 1920;               // N*640
  unsigned* count  = (unsigned*)(mlbuf + (size_t)N * 640);  // N
  unsigned* offs   = count + N;                             // N+1
  unsigned* cursor = offs + N + 1;                          // N
  unsigned* sorted = cursor + N;                            // E

  hipLaunchKernelGGL(init_count, dim3((N + 255) / 256), dim3(256), 0, stream, count, N);
  hipLaunchKernelGGL(k_hist, dim3((E + 255) / 256), dim3(256), 0, stream, eidx, count, E);
  hipLaunchKernelGGL(k_scan, dim3(1), dim3(1024), 0, stream, count, offs, cursor, N);
  hipLaunchKernelGGL(k_scatter, dim3((E + 255) / 256), dim3(256), 0, stream,
                     eidx, cursor, sorted, E);
  hipLaunchKernelGGL(k_wfold, dim3(80), dim3(256), 0, stream,
                     Wq0, Wq1, Wkv0, Wkv1, WATp, WBTp);
  hipLaunchKernelGGL(k_node, dim3((N + 15) / 16), dim3(256), 0, stream,
                     node, gamma0, gamma1, WATp, WBTp, Wsrc0, Wsrc1, Wdst0, Wdst1,
                     qkbuf, sbuf, dbuf, N);
  hipLaunchKernelGGL(k_agg, dim3((N + 3) / 4), dim3(256), 0, stream,
                     rbf, rsh, eidx, W_rbf, Wkv0, Wkv1, qkbuf, sbuf, dbuf,
                     offs, sorted, mlbuf, N, E);
  hipLaunchKernelGGL(k_out, dim3((N + 3) / 4), dim3(256), 0, stream,
                     node, mlbuf, Wmsg0, Wmsg1, out, N);
}